// Round 7
// baseline (345.311 us; speedup 1.0000x reference)
//
#include <hip/hip_runtime.h>
#include <hip/hip_bf16.h>

constexpr int N_DIM = 4096;
constexpr int BM = 128;
constexpr int BK = 32;
constexpr int NBLK = N_DIM / BM;     // 32
constexpr int SPLITK = 8;            // K-tiles (of 128) per chunk

using short8_t  = __attribute__((ext_vector_type(8))) short;
using ushort4_t = __attribute__((ext_vector_type(4))) unsigned short;
using f32x4     = __attribute__((ext_vector_type(4))) float;

struct hl_t { unsigned short h, l; };

__device__ __forceinline__ hl_t split1(float x) {
    __hip_bfloat16 bh = __float2bfloat16(x);          // RNE; bf16 keeps fp32 exponent range (no denormal hazard)
    float r = x - __bfloat162float(bh);
    __hip_bfloat16 bl = __float2bfloat16(r);
    hl_t out;
    out.h = __builtin_bit_cast(unsigned short, bh);
    out.l = __builtin_bit_cast(unsigned short, bl);
    return out;
}

__device__ __forceinline__ void gload_lds16(const unsigned short* g, unsigned short* l) {
    __builtin_amdgcn_global_load_lds(
        (const __attribute__((address_space(1))) unsigned int*)g,
        (__attribute__((address_space(3))) unsigned int*)l, 16, 0, 0);
}

// ---------------- Pre-pass: A -> AH/AL (row-major bf16 hi/lo), lower tiles only
__global__ __launch_bounds__(256) void convA_kernel(
    const float* __restrict__ A,
    unsigned short* __restrict__ AH, unsigned short* __restrict__ AL)
{
    const int j = (int)blockIdx.x, i = (int)blockIdx.y;
    if (i < j) return;                         // upper tiles never read by GEMM
    const int t  = (int)threadIdx.x;
    const int rg = t >> 5;                     // 0..7
    const int c4 = (t & 31) << 2;              // 0..124
    #pragma unroll 4
    for (int s = 0; s < 16; ++s) {
        const size_t r   = (size_t)i * BM + rg + s * 8;
        const size_t idx = r * N_DIM + (size_t)j * BM + c4;
        const float4 v = *reinterpret_cast<const float4*>(A + idx);
        ushort4_t h, l;
        hl_t r0 = split1(v.x); h[0] = r0.h; l[0] = r0.l;
        hl_t r1 = split1(v.y); h[1] = r1.h; l[1] = r1.l;
        hl_t r2 = split1(v.z); h[2] = r2.h; l[2] = r2.l;
        hl_t r3 = split1(v.w); h[3] = r3.h; l[3] = r3.l;
        *reinterpret_cast<ushort4_t*>(AH + idx) = h;
        *reinterpret_cast<ushort4_t*>(AL + idx) = l;
    }
}

// ---------------- Pre-pass: B -> BTH/BTL transposed ([col][k] bf16 hi/lo)
__global__ __launch_bounds__(256) void convB_kernel(
    const float* __restrict__ B,
    unsigned short* __restrict__ BTH, unsigned short* __restrict__ BTL)
{
    const int j = (int)blockIdx.x, i = (int)blockIdx.y;  // source tile: k-tile i, col-tile j
    if (i < j) return;                                   // B is tril: tiles i<j are zero/never read
    __shared__ float S[64][132];                         // 132 floats = 528B row stride, 16B-aligned
    const int t  = (int)threadIdx.x;
    const int rg = t >> 5;                    // 0..7   (stage rows)
    const int c4 = (t & 31) << 2;             // 0..124 (stage cols)
    const int kq = (t & 15) << 2;             // 0..60  (write: k quad)
    const int cg = t >> 4;                    // 0..15  (write: col group)
    for (int h0 = 0; h0 < BM; h0 += 64) {
        #pragma unroll 2
        for (int s = 0; s < 8; ++s) {
            const int k = rg + s * 8;         // 0..63
            const float4 v = *reinterpret_cast<const float4*>(
                B + ((size_t)(i * BM + h0 + k)) * N_DIM + (size_t)j * BM + c4);
            *reinterpret_cast<float4*>(&S[k][c4]) = v;
        }
        __syncthreads();
        #pragma unroll 2
        for (int s = 0; s < 8; ++s) {
            const int c = cg + s * 16;        // 0..127
            ushort4_t h, l;
            hl_t r0 = split1(S[kq + 0][c]); h[0] = r0.h; l[0] = r0.l;
            hl_t r1 = split1(S[kq + 1][c]); h[1] = r1.h; l[1] = r1.l;
            hl_t r2 = split1(S[kq + 2][c]); h[2] = r2.h; l[2] = r2.l;
            hl_t r3 = split1(S[kq + 3][c]); h[3] = r3.h; l[3] = r3.l;
            const size_t idx = ((size_t)(j * BM + c)) * N_DIM + (size_t)(i * BM) + h0 + kq;
            *reinterpret_cast<ushort4_t*>(BTH + idx) = h;
            *reinterpret_cast<ushort4_t*>(BTL + idx) = l;
        }
        __syncthreads();
    }
}

// ---------------- Main GEMM: C += tril-masked sum of 3 bf16-split terms
__global__ __launch_bounds__(256) void tril_gemm_kernel(
    const unsigned short* __restrict__ AH, const unsigned short* __restrict__ AL,
    const unsigned short* __restrict__ BTH, const unsigned short* __restrict__ BTL,
    float* __restrict__ C)
{
    // Decode linear block id -> (diag distance d, position, K-chunk), longest d first.
    int id = (int)blockIdx.x;
    int d = NBLK - 1, cnt;
    for (;;) {
        cnt = (NBLK - d) * ((d + SPLITK) >> 3);
        if (id < cnt) break;
        id -= cnt; --d;
    }
    const int nch = (d + SPLITK) >> 3;        // ceil((d+1)/8)
    const int pos = id / nch;
    const int ch  = id - pos * nch;
    const int bc = pos, br = pos + d;
    const int t0 = bc + ch * SPLITK;
    const int t1 = min(t0 + SPLITK, br + 1);
    const int ksteps = (t1 - t0) * (BM / BK); // <= 32

    __shared__ unsigned short LAh[BM][BK];
    __shared__ unsigned short LAl[BM][BK];
    __shared__ unsigned short LBh[BM][BK];
    __shared__ unsigned short LBl[BM][BK];

    const int tid  = (int)threadIdx.x;
    const int lane = tid & 63;
    const int wid  = tid >> 6;
    const int wrow = (wid >> 1) * 64;
    const int wcol = (wid & 1) * 64;
    const int g    = lane >> 4;               // k-group
    const int r16  = lane & 15;

    const size_t brow = (size_t)br * BM;
    const size_t bcol = (size_t)bc * BM;

    // Each wave stages one 128x32 bf16 plane per K-step (8 KB, 8 x 1KB chunks).
    const unsigned short* gplane =
        (wid == 0) ? AH : (wid == 1) ? AL : (wid == 2) ? BTH : BTL;
    unsigned short* lplane =
        (wid == 0) ? &LAh[0][0] : (wid == 1) ? &LAl[0][0] :
        (wid == 2) ? &LBh[0][0] : &LBl[0][0];
    const size_t growbase = (wid < 2) ? brow : bcol;
    const int srow  = lane >> 2;              // 0..15 within 16-row chunk
    const int selem = (lane & 3) * 8;         // k-element offset of this lane's 16B

    f32x4 acc[4][4] = {};

    for (int kt = 0; kt < ksteps; ++kt) {
        const size_t k0 = (size_t)t0 * BM + (size_t)kt * BK;
        #pragma unroll
        for (int q = 0; q < 8; ++q) {
            const unsigned short* gaddr =
                gplane + (growbase + q * 16 + srow) * N_DIM + k0 + selem;
            gload_lds16(gaddr, lplane + (q * 16) * BK);
        }
        __syncthreads();   // compiler drains vmcnt before s_barrier -> tile ready

        short8_t bh[4], bl[4];
        #pragma unroll
        for (int n = 0; n < 4; ++n) {
            bh[n] = *reinterpret_cast<const short8_t*>(&LBh[wcol + n * 16 + r16][g * 8]);
            bl[n] = *reinterpret_cast<const short8_t*>(&LBl[wcol + n * 16 + r16][g * 8]);
        }
        #pragma unroll
        for (int m = 0; m < 4; ++m) {
            const short8_t ah = *reinterpret_cast<const short8_t*>(&LAh[wrow + m * 16 + r16][g * 8]);
            const short8_t al = *reinterpret_cast<const short8_t*>(&LAl[wrow + m * 16 + r16][g * 8]);
            #pragma unroll
            for (int n = 0; n < 4; ++n) {
                acc[m][n] = __builtin_amdgcn_mfma_f32_16x16x32_bf16(ah, bh[n], acc[m][n], 0, 0, 0);
                acc[m][n] = __builtin_amdgcn_mfma_f32_16x16x32_bf16(ah, bl[n], acc[m][n], 0, 0, 0);
                acc[m][n] = __builtin_amdgcn_mfma_f32_16x16x32_bf16(al, bh[n], acc[m][n], 0, 0, 0);
            }
        }
        __syncthreads();   // frag reads done before next overwrite
    }

    // Epilogue: C/D layout col=lane&15, row=(lane>>4)*4+i (m89/m91-verified).
    const bool single = (nch == 1);
    #pragma unroll
    for (int m = 0; m < 4; ++m) {
        #pragma unroll
        for (int n = 0; n < 4; ++n) {
            #pragma unroll
            for (int i = 0; i < 4; ++i) {
                const size_t grow = brow + wrow + m * 16 + g * 4 + i;
                const size_t gcol = bcol + wcol + n * 16 + r16;
                if (gcol <= grow) {
                    if (single) C[grow * N_DIM + gcol] = acc[m][n][i];
                    else        atomicAdd(C + grow * N_DIM + gcol, acc[m][n][i]);
                }
            }
        }
    }
}

// ---------------- Fallback (ws too small): in-kernel-convert version
__global__ __launch_bounds__(256) void tril_mm_fallback(
    const float* __restrict__ A, const float* __restrict__ B, float* __restrict__ C)
{
    const int br  = (NBLK - 1) - (int)blockIdx.y;
    const int bc  = (int)blockIdx.x;
    const int tid = (int)threadIdx.x;

    __shared__ unsigned short Ah[BM][40];
    __shared__ unsigned short Al[BM][40];
    __shared__ unsigned short Bh[BM][40];
    __shared__ unsigned short Bl[BM][40];

    const int lane = tid & 63;
    const int wid  = tid >> 6;
    const int wrow = (wid >> 1) * 64;
    const int wcol = (wid & 1) * 64;
    const int g    = lane >> 4;
    const int r16  = lane & 15;

    const int brow = br * BM;
    const int bcol = bc * BM;
    const int ksteps = (br >= bc) ? (br - bc + 1) * (BM / BK) : 0;

    const int a_r = tid >> 3;
    const int a_c = (tid & 7) << 2;
    const int b_c  = tid & 127;
    const int b_kg = (tid >> 7) << 2;

    f32x4 acc[4][4] = {};
    float a_reg[4][4], b_reg[4][4];

    auto load_tiles = [&](int kt) {
        const int k0 = bcol + kt * BK;
        #pragma unroll
        for (int p = 0; p < 4; ++p) {
            const float4 av = *reinterpret_cast<const float4*>(
                A + (size_t)(brow + p * 32 + a_r) * N_DIM + (k0 + a_c));
            a_reg[p][0] = av.x; a_reg[p][1] = av.y;
            a_reg[p][2] = av.z; a_reg[p][3] = av.w;
            #pragma unroll
            for (int kk = 0; kk < 4; ++kk)
                b_reg[p][kk] = B[(size_t)(k0 + p * 8 + b_kg + kk) * N_DIM + (bcol + b_c)];
        }
    };

    if (ksteps > 0) load_tiles(0);

    for (int kt = 0; kt < ksteps; ++kt) {
        unsigned short ah[4][4], al[4][4], bh[4][4], bl[4][4];
        #pragma unroll
        for (int p = 0; p < 4; ++p)
            #pragma unroll
            for (int i = 0; i < 4; ++i) {
                hl_t ra = split1(a_reg[p][i]); ah[p][i] = ra.h; al[p][i] = ra.l;
                hl_t rb = split1(b_reg[p][i]); bh[p][i] = rb.h; bl[p][i] = rb.l;
            }
        __syncthreads();
        #pragma unroll
        for (int p = 0; p < 4; ++p) {
            ushort4_t va = {ah[p][0], ah[p][1], ah[p][2], ah[p][3]};
            ushort4_t vb = {al[p][0], al[p][1], al[p][2], al[p][3]};
            *reinterpret_cast<ushort4_t*>(&Ah[p * 32 + a_r][a_c]) = va;
            *reinterpret_cast<ushort4_t*>(&Al[p * 32 + a_r][a_c]) = vb;
            ushort4_t vc = {bh[p][0], bh[p][1], bh[p][2], bh[p][3]};
            ushort4_t vd = {bl[p][0], bl[p][1], bl[p][2], bl[p][3]};
            *reinterpret_cast<ushort4_t*>(&Bh[b_c][p * 8 + b_kg]) = vc;
            *reinterpret_cast<ushort4_t*>(&Bl[b_c][p * 8 + b_kg]) = vd;
        }
        __syncthreads();
        if (kt + 1 < ksteps) load_tiles(kt + 1);

        short8_t bhf[4], blf[4];
        #pragma unroll
        for (int n = 0; n < 4; ++n) {
            bhf[n] = *reinterpret_cast<const short8_t*>(&Bh[wcol + n * 16 + r16][g * 8]);
            blf[n] = *reinterpret_cast<const short8_t*>(&Bl[wcol + n * 16 + r16][g * 8]);
        }
        #pragma unroll
        for (int m = 0; m < 4; ++m) {
            const short8_t ahf = *reinterpret_cast<const short8_t*>(&Ah[wrow + m * 16 + r16][g * 8]);
            const short8_t alf = *reinterpret_cast<const short8_t*>(&Al[wrow + m * 16 + r16][g * 8]);
            #pragma unroll
            for (int n = 0; n < 4; ++n) {
                acc[m][n] = __builtin_amdgcn_mfma_f32_16x16x32_bf16(ahf, bhf[n], acc[m][n], 0, 0, 0);
                acc[m][n] = __builtin_amdgcn_mfma_f32_16x16x32_bf16(ahf, blf[n], acc[m][n], 0, 0, 0);
                acc[m][n] = __builtin_amdgcn_mfma_f32_16x16x32_bf16(alf, bhf[n], acc[m][n], 0, 0, 0);
            }
        }
    }

    #pragma unroll
    for (int m = 0; m < 4; ++m)
        #pragma unroll
        for (int n = 0; n < 4; ++n)
            #pragma unroll
            for (int i = 0; i < 4; ++i) {
                const int grow = brow + wrow + m * 16 + g * 4 + i;
                const int gcol = bcol + wcol + n * 16 + r16;
                C[(size_t)grow * N_DIM + gcol] = (gcol <= grow) ? acc[m][n][i] : 0.0f;
            }
}

static int gemm_total_blocks() {
    int total = 0;
    for (int d = 0; d < NBLK; ++d) total += (NBLK - d) * ((d + SPLITK) >> 3);
    return total;   // 1000
}

extern "C" void kernel_launch(void* const* d_in, const int* in_sizes, int n_in,
                              void* d_out, int out_size, void* d_ws, size_t ws_size,
                              hipStream_t stream) {
    const float* A = (const float*)d_in[0];
    const float* B = (const float*)d_in[1];
    float* C = (float*)d_out;

    const size_t plane = (size_t)N_DIM * N_DIM * sizeof(unsigned short); // 32 MB
    if (ws_size >= 4 * plane) {
        unsigned short* AH  = (unsigned short*)d_ws;
        unsigned short* AL  = AH  + (size_t)N_DIM * N_DIM;
        unsigned short* BTH = AL  + (size_t)N_DIM * N_DIM;
        unsigned short* BTL = BTH + (size_t)N_DIM * N_DIM;

        (void)hipMemsetAsync(d_out, 0, (size_t)out_size * sizeof(float), stream);
        convA_kernel<<<dim3(NBLK, NBLK), 256, 0, stream>>>(A, AH, AL);
        convB_kernel<<<dim3(NBLK, NBLK), 256, 0, stream>>>(B, BTH, BTL);
        tril_gemm_kernel<<<dim3(gemm_total_blocks()), 256, 0, stream>>>(AH, AL, BTH, BTL, C);
    } else {
        tril_mm_fallback<<<dim3(NBLK, NBLK), 256, 0, stream>>>(A, B, C);
    }
}

// Round 10
// 331.702 us; speedup vs baseline: 1.0410x; 1.0410x over previous
//
#include <hip/hip_runtime.h>
#include <hip/hip_bf16.h>

constexpr int N_DIM = 4096;
constexpr int BM = 128;
constexpr int BK = 32;
constexpr int NBLK = N_DIM / BM;     // 32
constexpr int SPLITK = 8;            // K-tiles (of 128) per chunk
constexpr int NXCD = 8;

using short8_t  = __attribute__((ext_vector_type(8))) short;
using ushort4_t = __attribute__((ext_vector_type(4))) unsigned short;
using f32x4     = __attribute__((ext_vector_type(4))) float;

struct hl_t { unsigned short h, l; };

__device__ __forceinline__ hl_t split1(float x) {
    __hip_bfloat16 bh = __float2bfloat16(x);          // RNE; bf16 keeps fp32 exponent range
    float r = x - __bfloat162float(bh);
    __hip_bfloat16 bl = __float2bfloat16(r);
    hl_t out;
    out.h = __builtin_bit_cast(unsigned short, bh);
    out.l = __builtin_bit_cast(unsigned short, bl);
    return out;
}

__device__ __forceinline__ void gload_lds16(const unsigned short* g, unsigned short* l) {
    __builtin_amdgcn_global_load_lds(
        (const __attribute__((address_space(1))) unsigned int*)g,
        (__attribute__((address_space(3))) unsigned int*)l, 16, 0, 0);
}

// ---------------- Pre-pass: A -> AH/AL (row-major bf16 hi/lo), lower tiles only
__global__ __launch_bounds__(256) void convA_kernel(
    const float* __restrict__ A,
    unsigned short* __restrict__ AH, unsigned short* __restrict__ AL)
{
    const int j = (int)blockIdx.x, i = (int)blockIdx.y;
    if (i < j) return;                         // upper tiles never read by GEMM
    const int t  = (int)threadIdx.x;
    const int rg = t >> 5;                     // 0..7
    const int c4 = (t & 31) << 2;              // 0..124
    #pragma unroll 4
    for (int s = 0; s < 16; ++s) {
        const size_t r   = (size_t)i * BM + rg + s * 8;
        const size_t idx = r * N_DIM + (size_t)j * BM + c4;
        const float4 v = *reinterpret_cast<const float4*>(A + idx);
        ushort4_t h, l;
        hl_t r0 = split1(v.x); h[0] = r0.h; l[0] = r0.l;
        hl_t r1 = split1(v.y); h[1] = r1.h; l[1] = r1.l;
        hl_t r2 = split1(v.z); h[2] = r2.h; l[2] = r2.l;
        hl_t r3 = split1(v.w); h[3] = r3.h; l[3] = r3.l;
        *reinterpret_cast<ushort4_t*>(AH + idx) = h;
        *reinterpret_cast<ushort4_t*>(AL + idx) = l;
    }
}

// ---------------- Pre-pass: B -> BTH/BTL transposed ([col][k] bf16 hi/lo)
// S stride 129 floats: 129 mod 32 == 1 -> transpose reads hit all 32 banks (2-way, free).
__global__ __launch_bounds__(256) void convB_kernel(
    const float* __restrict__ B,
    unsigned short* __restrict__ BTH, unsigned short* __restrict__ BTL)
{
    const int j = (int)blockIdx.x, i = (int)blockIdx.y;  // source tile: k-tile i, col-tile j
    if (i < j) return;                                   // B is tril: tiles i<j never read
    __shared__ float S[64][129];
    const int t  = (int)threadIdx.x;
    const int rg = t >> 5;                    // 0..7   (stage rows)
    const int c4 = (t & 31) << 2;             // 0..124 (stage cols)
    const int kq = (t & 15) << 2;             // 0..60  (write: k quad)
    const int cg = t >> 4;                    // 0..15  (write: col group)
    for (int h0 = 0; h0 < BM; h0 += 64) {
        #pragma unroll 2
        for (int s = 0; s < 8; ++s) {
            const int k = rg + s * 8;         // 0..63
            const float4 v = *reinterpret_cast<const float4*>(
                B + ((size_t)(i * BM + h0 + k)) * N_DIM + (size_t)j * BM + c4);
            S[k][c4 + 0] = v.x; S[k][c4 + 1] = v.y;
            S[k][c4 + 2] = v.z; S[k][c4 + 3] = v.w;
        }
        __syncthreads();
        #pragma unroll 2
        for (int s = 0; s < 8; ++s) {
            const int c = cg + s * 16;        // 0..127
            ushort4_t h, l;
            hl_t r0 = split1(S[kq + 0][c]); h[0] = r0.h; l[0] = r0.l;
            hl_t r1 = split1(S[kq + 1][c]); h[1] = r1.h; l[1] = r1.l;
            hl_t r2 = split1(S[kq + 2][c]); h[2] = r2.h; l[2] = r2.l;
            hl_t r3 = split1(S[kq + 3][c]); h[3] = r3.h; l[3] = r3.l;
            const size_t idx = ((size_t)(j * BM + c)) * N_DIM + (size_t)(i * BM) + h0 + kq;
            *reinterpret_cast<ushort4_t*>(BTH + idx) = h;
            *reinterpret_cast<ushort4_t*>(BTL + idx) = l;
        }
        __syncthreads();
    }
}

// ---------------- Main GEMM: C += tril-masked sum of 3 bf16-split terms
// Block order: row-panel-major (br descending), bc/chunk ascending within a row,
// XCD-chunked swizzle so each XCD owns contiguous rows -> A-strip (2MB) stays in
// its 4MB L2; B tiles get cross-row reuse. (Old d-major order: zero L2 sharing.)
__global__ __launch_bounds__(256) void tril_gemm_kernel(
    const unsigned short* __restrict__ AH, const unsigned short* __restrict__ AL,
    const unsigned short* __restrict__ BTH, const unsigned short* __restrict__ BTL,
    float* __restrict__ C, int nwg)
{
    // Bijective XCD swizzle (m204): nwg=1000 -> q=125, r=0.
    const int o = (int)blockIdx.x;
    const int q = nwg / NXCD, rr = nwg % NXCD;
    const int xcd = o % NXCD, idx = o / NXCD;
    const int logical = (xcd < rr ? xcd * (q + 1) : rr * (q + 1) + (xcd - rr) * q) + idx;

    // Decode: rows br = 31..0; row br has f(br+1) blocks, f(n) = sum_{k=1..n} ceil(k/8).
    int rem = logical;
    int br = NBLK - 1;
    for (;;) {
        const int n = br + 1;
        const int fq = n >> 3, fr = n & 7;
        const int fn = 4 * fq * (fq + 1) + fr * (fq + 1);   // f(n)
        if (rem < fn) break;
        rem -= fn; --br;
    }
    int bc = 0;
    for (;;) {
        const int nch = (br - bc + 8) >> 3;   // ceil((br-bc+1)/8)
        if (rem < nch) break;
        rem -= nch; ++bc;
    }
    const int ch  = rem;
    const int nch = (br - bc + 8) >> 3;
    const int t0 = bc + ch * SPLITK;
    const int t1 = min(t0 + SPLITK, br + 1);
    const int ksteps = (t1 - t0) * (BM / BK); // <= 32

    __shared__ unsigned short LAh[BM][BK];
    __shared__ unsigned short LAl[BM][BK];
    __shared__ unsigned short LBh[BM][BK];
    __shared__ unsigned short LBl[BM][BK];

    const int tid  = (int)threadIdx.x;
    const int lane = tid & 63;
    const int wid  = tid >> 6;
    const int wrow = (wid >> 1) * 64;
    const int wcol = (wid & 1) * 64;
    const int g    = lane >> 4;               // k-group
    const int r16  = lane & 15;

    const size_t brow = (size_t)br * BM;
    const size_t bcol = (size_t)bc * BM;

    // Each wave stages one 128x32 bf16 plane per K-step (8 KB, 8 x 1KB chunks).
    const unsigned short* gplane =
        (wid == 0) ? AH : (wid == 1) ? AL : (wid == 2) ? BTH : BTL;
    unsigned short* lplane =
        (wid == 0) ? &LAh[0][0] : (wid == 1) ? &LAl[0][0] :
        (wid == 2) ? &LBh[0][0] : &LBl[0][0];
    const size_t growbase = (wid < 2) ? brow : bcol;
    const int srow  = lane >> 2;              // 0..15 within 16-row chunk
    const int selem = (lane & 3) * 8;         // k-element offset of this lane's 16B

    f32x4 acc[4][4] = {};

    for (int kt = 0; kt < ksteps; ++kt) {
        const size_t k0 = (size_t)t0 * BM + (size_t)kt * BK;
        #pragma unroll
        for (int qq = 0; qq < 8; ++qq) {
            const unsigned short* gaddr =
                gplane + (growbase + qq * 16 + srow) * N_DIM + k0 + selem;
            gload_lds16(gaddr, lplane + (qq * 16) * BK);
        }
        __syncthreads();   // compiler drains vmcnt before s_barrier -> tile ready

        short8_t bh[4], bl[4];
        #pragma unroll
        for (int n = 0; n < 4; ++n) {
            bh[n] = *reinterpret_cast<const short8_t*>(&LBh[wcol + n * 16 + r16][g * 8]);
            bl[n] = *reinterpret_cast<const short8_t*>(&LBl[wcol + n * 16 + r16][g * 8]);
        }
        #pragma unroll
        for (int m = 0; m < 4; ++m) {
            const short8_t ah = *reinterpret_cast<const short8_t*>(&LAh[wrow + m * 16 + r16][g * 8]);
            const short8_t al = *reinterpret_cast<const short8_t*>(&LAl[wrow + m * 16 + r16][g * 8]);
            #pragma unroll
            for (int n = 0; n < 4; ++n) {
                acc[m][n] = __builtin_amdgcn_mfma_f32_16x16x32_bf16(ah, bh[n], acc[m][n], 0, 0, 0);
                acc[m][n] = __builtin_amdgcn_mfma_f32_16x16x32_bf16(ah, bl[n], acc[m][n], 0, 0, 0);
                acc[m][n] = __builtin_amdgcn_mfma_f32_16x16x32_bf16(al, bh[n], acc[m][n], 0, 0, 0);
            }
        }
        __syncthreads();   // frag reads done before next overwrite
    }

    // Epilogue: C/D layout col=lane&15, row=(lane>>4)*4+i (m89/m91-verified).
    const bool single = (nch == 1);
    #pragma unroll
    for (int m = 0; m < 4; ++m) {
        #pragma unroll
        for (int n = 0; n < 4; ++n) {
            #pragma unroll
            for (int i = 0; i < 4; ++i) {
                const size_t grow = brow + wrow + m * 16 + g * 4 + i;
                const size_t gcol = bcol + wcol + n * 16 + r16;
                if (gcol <= grow) {
                    if (single) C[grow * N_DIM + gcol] = acc[m][n][i];
                    else        atomicAdd(C + grow * N_DIM + gcol, acc[m][n][i]);
                }
            }
        }
    }
}

// ---------------- Fallback (ws too small): in-kernel-convert version
__global__ __launch_bounds__(256) void tril_mm_fallback(
    const float* __restrict__ A, const float* __restrict__ B, float* __restrict__ C)
{
    const int br  = (NBLK - 1) - (int)blockIdx.y;
    const int bc  = (int)blockIdx.x;
    const int tid = (int)threadIdx.x;

    __shared__ unsigned short Ah[BM][40];
    __shared__ unsigned short Al[BM][40];
    __shared__ unsigned short Bh[BM][40];
    __shared__ unsigned short Bl[BM][40];

    const int lane = tid & 63;
    const int wid  = tid >> 6;
    const int wrow = (wid >> 1) * 64;
    const int wcol = (wid & 1) * 64;
    const int g    = lane >> 4;
    const int r16  = lane & 15;

    const int brow = br * BM;
    const int bcol = bc * BM;
    const int ksteps = (br >= bc) ? (br - bc + 1) * (BM / BK) : 0;

    const int a_r = tid >> 3;
    const int a_c = (tid & 7) << 2;
    const int b_c  = tid & 127;
    const int b_kg = (tid >> 7) << 2;

    f32x4 acc[4][4] = {};
    float a_reg[4][4], b_reg[4][4];

    auto load_tiles = [&](int kt) {
        const int k0 = bcol + kt * BK;
        #pragma unroll
        for (int p = 0; p < 4; ++p) {
            const float4 av = *reinterpret_cast<const float4*>(
                A + (size_t)(brow + p * 32 + a_r) * N_DIM + (k0 + a_c));
            a_reg[p][0] = av.x; a_reg[p][1] = av.y;
            a_reg[p][2] = av.z; a_reg[p][3] = av.w;
            #pragma unroll
            for (int kk = 0; kk < 4; ++kk)
                b_reg[p][kk] = B[(size_t)(k0 + p * 8 + b_kg + kk) * N_DIM + (bcol + b_c)];
        }
    };

    if (ksteps > 0) load_tiles(0);

    for (int kt = 0; kt < ksteps; ++kt) {
        unsigned short ah[4][4], al[4][4], bh[4][4], bl[4][4];
        #pragma unroll
        for (int p = 0; p < 4; ++p)
            #pragma unroll
            for (int i = 0; i < 4; ++i) {
                hl_t ra = split1(a_reg[p][i]); ah[p][i] = ra.h; al[p][i] = ra.l;
                hl_t rb = split1(b_reg[p][i]); bh[p][i] = rb.h; bl[p][i] = rb.l;
            }
        __syncthreads();
        #pragma unroll
        for (int p = 0; p < 4; ++p) {
            ushort4_t va = {ah[p][0], ah[p][1], ah[p][2], ah[p][3]};
            ushort4_t vb = {al[p][0], al[p][1], al[p][2], al[p][3]};
            *reinterpret_cast<ushort4_t*>(&Ah[p * 32 + a_r][a_c]) = va;
            *reinterpret_cast<ushort4_t*>(&Al[p * 32 + a_r][a_c]) = vb;
            ushort4_t vc = {bh[p][0], bh[p][1], bh[p][2], bh[p][3]};
            ushort4_t vd = {bl[p][0], bl[p][1], bl[p][2], bl[p][3]};
            *reinterpret_cast<ushort4_t*>(&Bh[b_c][p * 8 + b_kg]) = vc;
            *reinterpret_cast<ushort4_t*>(&Bl[b_c][p * 8 + b_kg]) = vd;
        }
        __syncthreads();
        if (kt + 1 < ksteps) load_tiles(kt + 1);

        short8_t bhf[4], blf[4];
        #pragma unroll
        for (int n = 0; n < 4; ++n) {
            bhf[n] = *reinterpret_cast<const short8_t*>(&Bh[wcol + n * 16 + r16][g * 8]);
            blf[n] = *reinterpret_cast<const short8_t*>(&Bl[wcol + n * 16 + r16][g * 8]);
        }
        #pragma unroll
        for (int m = 0; m < 4; ++m) {
            const short8_t ahf = *reinterpret_cast<const short8_t*>(&Ah[wrow + m * 16 + r16][g * 8]);
            const short8_t alf = *reinterpret_cast<const short8_t*>(&Al[wrow + m * 16 + r16][g * 8]);
            #pragma unroll
            for (int n = 0; n < 4; ++n) {
                acc[m][n] = __builtin_amdgcn_mfma_f32_16x16x32_bf16(ahf, bhf[n], acc[m][n], 0, 0, 0);
                acc[m][n] = __builtin_amdgcn_mfma_f32_16x16x32_bf16(ahf, blf[n], acc[m][n], 0, 0, 0);
                acc[m][n] = __builtin_amdgcn_mfma_f32_16x16x32_bf16(alf, bhf[n], acc[m][n], 0, 0, 0);
            }
        }
    }

    #pragma unroll
    for (int m = 0; m < 4; ++m)
        #pragma unroll
        for (int n = 0; n < 4; ++n)
            #pragma unroll
            for (int i = 0; i < 4; ++i) {
                const int grow = brow + wrow + m * 16 + g * 4 + i;
                const int gcol = bcol + wcol + n * 16 + r16;
                C[(size_t)grow * N_DIM + gcol] = (gcol <= grow) ? acc[m][n][i] : 0.0f;
            }
}

static int gemm_total_blocks() {
    int total = 0;
    for (int d = 0; d < NBLK; ++d) total += (NBLK - d) * ((d + SPLITK) >> 3);
    return total;   // 1000
}

extern "C" void kernel_launch(void* const* d_in, const int* in_sizes, int n_in,
                              void* d_out, int out_size, void* d_ws, size_t ws_size,
                              hipStream_t stream) {
    const float* A = (const float*)d_in[0];
    const float* B = (const float*)d_in[1];
    float* C = (float*)d_out;

    const size_t plane = (size_t)N_DIM * N_DIM * sizeof(unsigned short); // 32 MB
    if (ws_size >= 4 * plane) {
        unsigned short* AH  = (unsigned short*)d_ws;
        unsigned short* AL  = AH  + (size_t)N_DIM * N_DIM;
        unsigned short* BTH = AL  + (size_t)N_DIM * N_DIM;
        unsigned short* BTL = BTH + (size_t)N_DIM * N_DIM;

        (void)hipMemsetAsync(d_out, 0, (size_t)out_size * sizeof(float), stream);
        convA_kernel<<<dim3(NBLK, NBLK), 256, 0, stream>>>(A, AH, AL);
        convB_kernel<<<dim3(NBLK, NBLK), 256, 0, stream>>>(B, BTH, BTL);
        const int nwg = gemm_total_blocks();
        tril_gemm_kernel<<<dim3(nwg), 256, 0, stream>>>(AH, AL, BTH, BTL, C, nwg);
    } else {
        tril_mm_fallback<<<dim3(NBLK, NBLK), 256, 0, stream>>>(A, B, C);
    }
}

// Round 11
// 292.145 us; speedup vs baseline: 1.1820x; 1.1354x over previous
//
#include <hip/hip_runtime.h>
#include <hip/hip_bf16.h>

constexpr int N_DIM = 4096;
constexpr int BM = 128;
constexpr int BK = 32;
constexpr int NBLK = N_DIM / BM;     // 32
constexpr int SPLITK = 8;            // K-tiles (of 128) per chunk
constexpr int NXCD = 8;

using short8_t  = __attribute__((ext_vector_type(8))) short;
using ushort4_t = __attribute__((ext_vector_type(4))) unsigned short;
using f32x4     = __attribute__((ext_vector_type(4))) float;

struct hl_t { unsigned short h, l; };

__device__ __forceinline__ hl_t split1(float x) {
    __hip_bfloat16 bh = __float2bfloat16(x);          // RNE; bf16 keeps fp32 exponent range
    float r = x - __bfloat162float(bh);
    __hip_bfloat16 bl = __float2bfloat16(r);
    hl_t out;
    out.h = __builtin_bit_cast(unsigned short, bh);
    out.l = __builtin_bit_cast(unsigned short, bl);
    return out;
}

__device__ __forceinline__ void gload_lds16(const unsigned short* g, unsigned short* l) {
    __builtin_amdgcn_global_load_lds(
        (const __attribute__((address_space(1))) unsigned int*)g,
        (__attribute__((address_space(3))) unsigned int*)l, 16, 0, 0);
}

// ---------------- Fused prep: convA-tiles | convB-tiles | C-zero, one dispatch.
// All jobs independent -> run concurrently (was 3 serialized launches = 165us).
__global__ __launch_bounds__(256) void prep_kernel(
    const float* __restrict__ A, const float* __restrict__ B,
    unsigned short* __restrict__ AH, unsigned short* __restrict__ AL,
    unsigned short* __restrict__ BTH, unsigned short* __restrict__ BTL,
    float* __restrict__ C)
{
    __shared__ float S[64][129];   // convB transpose buffer; 129 % 32 == 1 -> conflict-free
    const int bid = (int)blockIdx.x;
    const int t   = (int)threadIdx.x;

    if (bid < 1024) {
        // ---- convA tile (i,j), lower only
        const int j = bid & 31, i = bid >> 5;
        if (i < j) return;
        const int rg = t >> 5;                 // 0..7
        const int c4 = (t & 31) << 2;          // 0..124
        #pragma unroll 4
        for (int s = 0; s < 16; ++s) {
            const size_t r   = (size_t)i * BM + rg + s * 8;
            const size_t idx = r * N_DIM + (size_t)j * BM + c4;
            const float4 v = *reinterpret_cast<const float4*>(A + idx);
            ushort4_t h, l;
            hl_t r0 = split1(v.x); h[0] = r0.h; l[0] = r0.l;
            hl_t r1 = split1(v.y); h[1] = r1.h; l[1] = r1.l;
            hl_t r2 = split1(v.z); h[2] = r2.h; l[2] = r2.l;
            hl_t r3 = split1(v.w); h[3] = r3.h; l[3] = r3.l;
            *reinterpret_cast<ushort4_t*>(AH + idx) = h;
            *reinterpret_cast<ushort4_t*>(AL + idx) = l;
        }
    } else if (bid < 2048) {
        // ---- convB tile: k-tile i, col-tile j -> BT [col][k], lower (i>=j) only
        const int id = bid - 1024;
        const int j = id & 31, i = id >> 5;
        if (i < j) return;
        const int rg = t >> 5;                 // 0..7   (stage rows)
        const int c4 = (t & 31) << 2;          // 0..124 (stage cols)
        const int kq = (t & 15) << 2;          // 0..60  (write: k quad)
        const int cg = t >> 4;                 // 0..15  (write: col group)
        for (int h0 = 0; h0 < BM; h0 += 64) {
            #pragma unroll 2
            for (int s = 0; s < 8; ++s) {
                const int k = rg + s * 8;      // 0..63
                const float4 v = *reinterpret_cast<const float4*>(
                    B + ((size_t)(i * BM + h0 + k)) * N_DIM + (size_t)j * BM + c4);
                S[k][c4 + 0] = v.x; S[k][c4 + 1] = v.y;
                S[k][c4 + 2] = v.z; S[k][c4 + 3] = v.w;
            }
            __syncthreads();
            #pragma unroll 2
            for (int s = 0; s < 8; ++s) {
                const int c = cg + s * 16;     // 0..127
                ushort4_t h, l;
                hl_t r0 = split1(S[kq + 0][c]); h[0] = r0.h; l[0] = r0.l;
                hl_t r1 = split1(S[kq + 1][c]); h[1] = r1.h; l[1] = r1.l;
                hl_t r2 = split1(S[kq + 2][c]); h[2] = r2.h; l[2] = r2.l;
                hl_t r3 = split1(S[kq + 3][c]); h[3] = r3.h; l[3] = r3.l;
                const size_t idx = ((size_t)(j * BM + c)) * N_DIM + (size_t)(i * BM) + h0 + kq;
                *reinterpret_cast<ushort4_t*>(BTH + idx) = h;
                *reinterpret_cast<ushort4_t*>(BTL + idx) = l;
            }
            __syncthreads();
        }
    } else {
        // ---- C zero: 512 blocks x 8192 float4 = 64 MB
        const int z = bid - 2048;
        const float4 zero = {0.f, 0.f, 0.f, 0.f};
        float4* p = reinterpret_cast<float4*>(C) + (size_t)z * 8192 + t;
        #pragma unroll
        for (int s = 0; s < 32; ++s) p[s * 256] = zero;
    }
}

// ---------------- Main GEMM: 2-phase double-buffered LDS (T3 minimum recipe).
// stage(next) issued BEFORE compute(cur) -> HBM/L2 latency hides under MFMA;
// ONE __syncthreads per K-step (drains stage loads + frag reads together).
__global__ __launch_bounds__(256) void tril_gemm_kernel(
    const unsigned short* __restrict__ AH, const unsigned short* __restrict__ AL,
    const unsigned short* __restrict__ BTH, const unsigned short* __restrict__ BTL,
    float* __restrict__ C, int nwg)
{
    // Bijective XCD swizzle (m204): nwg=1000 -> q=125, rr=0.
    const int o = (int)blockIdx.x;
    const int q = nwg / NXCD, rr = nwg % NXCD;
    const int xcd = o % NXCD, idx = o / NXCD;
    const int logical = (xcd < rr ? xcd * (q + 1) : rr * (q + 1) + (xcd - rr) * q) + idx;

    // Decode: rows br = 31..0; row br has f(br+1) blocks, f(n) = sum_{k=1..n} ceil(k/8).
    int rem = logical;
    int br = NBLK - 1;
    for (;;) {
        const int n = br + 1;
        const int fq = n >> 3, fr = n & 7;
        const int fn = 4 * fq * (fq + 1) + fr * (fq + 1);   // f(n)
        if (rem < fn) break;
        rem -= fn; --br;
    }
    int bc = 0;
    for (;;) {
        const int nch = (br - bc + 8) >> 3;   // ceil((br-bc+1)/8)
        if (rem < nch) break;
        rem -= nch; ++bc;
    }
    const int ch  = rem;
    const int nch = (br - bc + 8) >> 3;
    const int t0 = bc + ch * SPLITK;
    const int t1 = min(t0 + SPLITK, br + 1);
    const int ksteps = (t1 - t0) * (BM / BK); // <= 32

    // Double-buffered: 2 bufs x 4 planes (Ah,Al,Bh,Bl) x 8 KB = 64 KB.
    __shared__ unsigned short L[2][4][BM * BK];

    const int tid  = (int)threadIdx.x;
    const int lane = tid & 63;
    const int wid  = tid >> 6;
    const int wrow = (wid >> 1) * 64;
    const int wcol = (wid & 1) * 64;
    const int g    = lane >> 4;               // k-group
    const int r16  = lane & 15;

    const size_t brow = (size_t)br * BM;
    const size_t bcol = (size_t)bc * BM;

    // Each wave stages one 128x32 bf16 plane per K-step (8 KB, 8 x 1KB chunks).
    const unsigned short* gplane =
        (wid == 0) ? AH : (wid == 1) ? AL : (wid == 2) ? BTH : BTL;
    const size_t growbase = (wid < 2) ? brow : bcol;
    const int srow  = lane >> 2;              // 0..15 within 16-row chunk
    const int selem = (lane & 3) * 8;         // k-element offset of this lane's 16B

    auto stage = [&](int buf, int kt) {
        const size_t k0 = (size_t)t0 * BM + (size_t)kt * BK;
        unsigned short* ldst = &L[buf][wid][0];
        #pragma unroll
        for (int qq = 0; qq < 8; ++qq) {
            const unsigned short* gaddr =
                gplane + (growbase + qq * 16 + srow) * N_DIM + k0 + selem;
            gload_lds16(gaddr, ldst + qq * 16 * BK);
        }
    };

    f32x4 acc[4][4] = {};

    stage(0, 0);
    __syncthreads();                           // buf0 landed
    int cur = 0;
    for (int kt = 0; kt < ksteps; ++kt) {
        if (kt + 1 < ksteps) stage(cur ^ 1, kt + 1);   // loads fly under compute

        short8_t bh[4], bl[4];
        #pragma unroll
        for (int n = 0; n < 4; ++n) {
            bh[n] = *reinterpret_cast<const short8_t*>(&L[cur][2][(wcol + n * 16 + r16) * BK + g * 8]);
            bl[n] = *reinterpret_cast<const short8_t*>(&L[cur][3][(wcol + n * 16 + r16) * BK + g * 8]);
        }
        #pragma unroll
        for (int m = 0; m < 4; ++m) {
            const short8_t ah = *reinterpret_cast<const short8_t*>(&L[cur][0][(wrow + m * 16 + r16) * BK + g * 8]);
            const short8_t al = *reinterpret_cast<const short8_t*>(&L[cur][1][(wrow + m * 16 + r16) * BK + g * 8]);
            #pragma unroll
            for (int n = 0; n < 4; ++n) {
                acc[m][n] = __builtin_amdgcn_mfma_f32_16x16x32_bf16(ah, bh[n], acc[m][n], 0, 0, 0);
                acc[m][n] = __builtin_amdgcn_mfma_f32_16x16x32_bf16(ah, bl[n], acc[m][n], 0, 0, 0);
                acc[m][n] = __builtin_amdgcn_mfma_f32_16x16x32_bf16(al, bh[n], acc[m][n], 0, 0, 0);
            }
        }
        __syncthreads();   // drains next-tile stage loads AND all frag reads of buf[cur]
        cur ^= 1;
    }

    // Epilogue: C/D layout col=lane&15, row=(lane>>4)*4+i (m89/m91-verified).
    const bool single = (nch == 1);
    #pragma unroll
    for (int m = 0; m < 4; ++m) {
        #pragma unroll
        for (int n = 0; n < 4; ++n) {
            #pragma unroll
            for (int i = 0; i < 4; ++i) {
                const size_t grow = brow + wrow + m * 16 + g * 4 + i;
                const size_t gcol = bcol + wcol + n * 16 + r16;
                if (gcol <= grow) {
                    if (single) C[grow * N_DIM + gcol] = acc[m][n][i];
                    else        atomicAdd(C + grow * N_DIM + gcol, acc[m][n][i]);
                }
            }
        }
    }
}

// ---------------- Fallback (ws too small): in-kernel-convert version
__global__ __launch_bounds__(256) void tril_mm_fallback(
    const float* __restrict__ A, const float* __restrict__ B, float* __restrict__ C)
{
    const int br  = (NBLK - 1) - (int)blockIdx.y;
    const int bc  = (int)blockIdx.x;
    const int tid = (int)threadIdx.x;

    __shared__ unsigned short Ah[BM][40];
    __shared__ unsigned short Al[BM][40];
    __shared__ unsigned short Bh[BM][40];
    __shared__ unsigned short Bl[BM][40];

    const int lane = tid & 63;
    const int wid  = tid >> 6;
    const int wrow = (wid >> 1) * 64;
    const int wcol = (wid & 1) * 64;
    const int g    = lane >> 4;
    const int r16  = lane & 15;

    const int brow = br * BM;
    const int bcol = bc * BM;
    const int ksteps = (br >= bc) ? (br - bc + 1) * (BM / BK) : 0;

    const int a_r = tid >> 3;
    const int a_c = (tid & 7) << 2;
    const int b_c  = tid & 127;
    const int b_kg = (tid >> 7) << 2;

    f32x4 acc[4][4] = {};
    float a_reg[4][4], b_reg[4][4];

    auto load_tiles = [&](int kt) {
        const int k0 = bcol + kt * BK;
        #pragma unroll
        for (int p = 0; p < 4; ++p) {
            const float4 av = *reinterpret_cast<const float4*>(
                A + (size_t)(brow + p * 32 + a_r) * N_DIM + (k0 + a_c));
            a_reg[p][0] = av.x; a_reg[p][1] = av.y;
            a_reg[p][2] = av.z; a_reg[p][3] = av.w;
            #pragma unroll
            for (int kk = 0; kk < 4; ++kk)
                b_reg[p][kk] = B[(size_t)(k0 + p * 8 + b_kg + kk) * N_DIM + (bcol + b_c)];
        }
    };

    if (ksteps > 0) load_tiles(0);

    for (int kt = 0; kt < ksteps; ++kt) {
        unsigned short ah[4][4], al[4][4], bh[4][4], bl[4][4];
        #pragma unroll
        for (int p = 0; p < 4; ++p)
            #pragma unroll
            for (int i = 0; i < 4; ++i) {
                hl_t ra = split1(a_reg[p][i]); ah[p][i] = ra.h; al[p][i] = ra.l;
                hl_t rb = split1(b_reg[p][i]); bh[p][i] = rb.h; bl[p][i] = rb.l;
            }
        __syncthreads();
        #pragma unroll
        for (int p = 0; p < 4; ++p) {
            ushort4_t va = {ah[p][0], ah[p][1], ah[p][2], ah[p][3]};
            ushort4_t vb = {al[p][0], al[p][1], al[p][2], al[p][3]};
            *reinterpret_cast<ushort4_t*>(&Ah[p * 32 + a_r][a_c]) = va;
            *reinterpret_cast<ushort4_t*>(&Al[p * 32 + a_r][a_c]) = vb;
            ushort4_t vc = {bh[p][0], bh[p][1], bh[p][2], bh[p][3]};
            ushort4_t vd = {bl[p][0], bl[p][1], bl[p][2], bl[p][3]};
            *reinterpret_cast<ushort4_t*>(&Bh[b_c][p * 8 + b_kg]) = vc;
            *reinterpret_cast<ushort4_t*>(&Bl[b_c][p * 8 + b_kg]) = vd;
        }
        __syncthreads();
        if (kt + 1 < ksteps) load_tiles(kt + 1);

        short8_t bhf[4], blf[4];
        #pragma unroll
        for (int n = 0; n < 4; ++n) {
            bhf[n] = *reinterpret_cast<const short8_t*>(&Bh[wcol + n * 16 + r16][g * 8]);
            blf[n] = *reinterpret_cast<const short8_t*>(&Bl[wcol + n * 16 + r16][g * 8]);
        }
        #pragma unroll
        for (int m = 0; m < 4; ++m) {
            const short8_t ahf = *reinterpret_cast<const short8_t*>(&Ah[wrow + m * 16 + r16][g * 8]);
            const short8_t alf = *reinterpret_cast<const short8_t*>(&Al[wrow + m * 16 + r16][g * 8]);
            #pragma unroll
            for (int n = 0; n < 4; ++n) {
                acc[m][n] = __builtin_amdgcn_mfma_f32_16x16x32_bf16(ahf, bhf[n], acc[m][n], 0, 0, 0);
                acc[m][n] = __builtin_amdgcn_mfma_f32_16x16x32_bf16(ahf, blf[n], acc[m][n], 0, 0, 0);
                acc[m][n] = __builtin_amdgcn_mfma_f32_16x16x32_bf16(alf, bhf[n], acc[m][n], 0, 0, 0);
            }
        }
    }

    #pragma unroll
    for (int m = 0; m < 4; ++m)
        #pragma unroll
        for (int n = 0; n < 4; ++n)
            #pragma unroll
            for (int i = 0; i < 4; ++i) {
                const int grow = brow + wrow + m * 16 + g * 4 + i;
                const int gcol = bcol + wcol + n * 16 + r16;
                C[(size_t)grow * N_DIM + gcol] = (gcol <= grow) ? acc[m][n][i] : 0.0f;
            }
}

static int gemm_total_blocks() {
    int total = 0;
    for (int d = 0; d < NBLK; ++d) total += (NBLK - d) * ((d + SPLITK) >> 3);
    return total;   // 1000
}

extern "C" void kernel_launch(void* const* d_in, const int* in_sizes, int n_in,
                              void* d_out, int out_size, void* d_ws, size_t ws_size,
                              hipStream_t stream) {
    const float* A = (const float*)d_in[0];
    const float* B = (const float*)d_in[1];
    float* C = (float*)d_out;

    const size_t plane = (size_t)N_DIM * N_DIM * sizeof(unsigned short); // 32 MB
    if (ws_size >= 4 * plane) {
        unsigned short* AH  = (unsigned short*)d_ws;
        unsigned short* AL  = AH  + (size_t)N_DIM * N_DIM;
        unsigned short* BTH = AL  + (size_t)N_DIM * N_DIM;
        unsigned short* BTL = BTH + (size_t)N_DIM * N_DIM;

        prep_kernel<<<dim3(2560), 256, 0, stream>>>(A, B, AH, AL, BTH, BTL, C);
        const int nwg = gemm_total_blocks();
        tril_gemm_kernel<<<dim3(nwg), 256, 0, stream>>>(AH, AL, BTH, BTL, C, nwg);
    } else {
        tril_mm_fallback<<<dim3(NBLK, NBLK), 256, 0, stream>>>(A, B, C);
    }
}